// Round 1
// baseline (459.210 us; speedup 1.0000x reference)
//
#include <hip/hip_runtime.h>

#define M_ 4
#define K_ 2048
#define D_ 32
#define N_ 8
#define H_ 64
#define W_ 64
#define HW_ (H_*W_)
#define NHW_ (N_*HW_)
#define C_ (M_*D_)
#define KT_ 64
#define NTILES (K_/KT_)

// One block = 256 threads = 4 waves. wave index == m (codebook group),
// lane == spatial position within a 64-position chunk. Codebook staged in
// LDS in 64-code tiles; inner-loop LDS reads are wave-uniform broadcasts.
__global__ __launch_bounds__(256) void qenc_argmax_kernel(
    const float* __restrict__ latent,
    const float* __restrict__ codebook,
    int* __restrict__ out)
{
    __shared__ float s_cb[M_][KT_][D_];   // 32 KiB
    __shared__ float s_h[M_][KT_];        // 1 KiB: h = 0.5*||c||^2

    const int tid  = threadIdx.x;
    const int m    = tid >> 6;            // wave id == m
    const int lane = tid & 63;
    const int pos  = blockIdx.x * 64 + lane;   // 0..NHW_-1 (grid = NHW_/64)
    const int n    = pos >> 12;           // HW_ = 4096
    const int hw   = pos & (HW_ - 1);

    // q[d] = latent[n][m*32+d][h][w]; consecutive lanes -> consecutive hw
    // (blocks of 64 never straddle an image: 4096 % 64 == 0) -> coalesced.
    float q[D_];
    const float* lp = latent + ((size_t)n * C_ + m * D_) * HW_ + hw;
    #pragma unroll
    for (int d = 0; d < D_; ++d) q[d] = lp[(size_t)d * HW_];

    float best = -3.402823466e+38f;
    int   bi   = 0;

    for (int t = 0; t < NTILES; ++t) {
        __syncthreads();  // previous tile fully consumed before overwrite

        // Stage codebook tile: M_*KT_*D_/4 = 2048 float4, 8 per thread.
        // ve = tid + i*256 -> consecutive lanes read consecutive float4
        // (coalesced) and write consecutive LDS float4 (minimal bank aliasing).
        {
            const float4* src = reinterpret_cast<const float4*>(codebook);
            float4* dst = reinterpret_cast<float4*>(&s_cb[0][0][0]);
            #pragma unroll
            for (int i = 0; i < 8; ++i) {
                int ve  = tid + i * 256;          // 0..2047
                int mp  = ve >> 9;                // 512 float4 per m
                int rem = ve & 511;
                dst[ve] = src[((size_t)mp * K_ + (size_t)t * KT_) * (D_/4) + rem];
            }
            // h for exactly one (m,k) per thread, read from global (L2-hot);
            // avoids LDS bank-conflicted row reads and needs no extra barrier.
            int mp = tid >> 6;
            int kk = tid & 63;
            const float4* row = reinterpret_cast<const float4*>(
                codebook + ((size_t)mp * K_ + (size_t)t * KT_ + kk) * D_);
            float c2 = 0.f;
            #pragma unroll
            for (int v = 0; v < 8; ++v) {
                float4 cv = row[v];
                c2 = fmaf(cv.x, cv.x, c2);
                c2 = fmaf(cv.y, cv.y, c2);
                c2 = fmaf(cv.z, cv.z, c2);
                c2 = fmaf(cv.w, cv.w, c2);
            }
            s_h[mp][kk] = 0.5f * c2;
        }
        __syncthreads();

        // score = dot(q,c) - 0.5*||c||^2  (same argmax as 2*dot - ||c||^2).
        // All lanes of a wave read the same LDS address -> broadcast, free.
        const float4* crow = reinterpret_cast<const float4*>(&s_cb[m][0][0]);
        #pragma unroll 2
        for (int kk = 0; kk < KT_; ++kk) {
            float d0 = 0.f, d1 = 0.f, d2 = 0.f, d3 = 0.f;
            #pragma unroll
            for (int v = 0; v < 8; ++v) {
                float4 cv = crow[kk * 8 + v];
                d0 = fmaf(q[v*4+0], cv.x, d0);
                d1 = fmaf(q[v*4+1], cv.y, d1);
                d2 = fmaf(q[v*4+2], cv.z, d2);
                d3 = fmaf(q[v*4+3], cv.w, d3);
            }
            float score = ((d0 + d1) + (d2 + d3)) - s_h[m][kk];
            int k = t * KT_ + kk;
            if (score > best) { best = score; bi = k; }  // strict >: first-max, matches jnp.argmax
        }
    }

    // out[n][h][w][m]
    out[(size_t)pos * M_ + m] = bi;
}

extern "C" void kernel_launch(void* const* d_in, const int* in_sizes, int n_in,
                              void* d_out, int out_size, void* d_ws, size_t ws_size,
                              hipStream_t stream) {
    const float* latent   = (const float*)d_in[0];
    const float* codebook = (const float*)d_in[1];
    int* out = (int*)d_out;
    qenc_argmax_kernel<<<NHW_ / 64, 256, 0, stream>>>(latent, codebook, out);
}

// Round 2
// 115.226 us; speedup vs baseline: 3.9853x; 3.9853x over previous
//
#include <hip/hip_runtime.h>

#define M_ 4
#define K_ 2048
#define D_ 32
#define HW_ 4096
#define NHW_ 32768
#define NT 128                      // K_/16 codebook tiles

// workspace layout (bytes)
#define CBH_OFF 0                                   // bf16 hi  [4][2048][32]
#define CBL_OFF (M_*K_*D_*2)                        // bf16 lo  (512 KiB each)
#define H_OFF   (CBL_OFF*2)                         // f32 0.5*||c||^2 [4][2048]
#define K1_OFF  (H_OFF + M_*K_*4)                   // i32 best idx  [4][32768]
#define K2_OFF  (K1_OFF + M_*NHW_*4)                // i32 2nd idx   [4][32768]

typedef __attribute__((ext_vector_type(8))) short bf16x8;
typedef __attribute__((ext_vector_type(4))) float f32x4;

// round-to-nearest-even fp32 -> bf16 (bit pattern), also returns the fp32 value back
__device__ __forceinline__ short bf16_rte(float x, float* back) {
    unsigned u = __float_as_uint(x);
    unsigned r = (u + 0x7FFFu + ((u >> 16) & 1u)) >> 16;
    *back = __uint_as_float(r << 16);
    return (short)(r & 0xFFFFu);
}

// ---- kernel 1: split codebook into bf16 hi/lo, compute h = 0.5*||c||^2 ----
__global__ __launch_bounds__(256) void prep_kernel(const float* __restrict__ cb,
                                                   unsigned char* __restrict__ ws) {
    int t = blockIdx.x * 256 + threadIdx.x;          // row id = m*K_ + k, 0..8191
    const float* src = cb + (size_t)t * D_;
    short* dh = (short*)(ws + CBH_OFF) + (size_t)t * D_;
    short* dl = (short*)(ws + CBL_OFF) + (size_t)t * D_;
    float* hp = (float*)(ws + H_OFF);
    bf16x8 vh[4], vl[4];
    float c2 = 0.f;
    #pragma unroll
    for (int d = 0; d < D_; ++d) {
        float x = src[d];
        float hf, lf;
        short hb = bf16_rte(x, &hf);
        short lb = bf16_rte(x - hf, &lf);
        vh[d >> 3][d & 7] = hb;
        vl[d >> 3][d & 7] = lb;
        c2 = fmaf(x, x, c2);
    }
    #pragma unroll
    for (int i = 0; i < 4; ++i) {
        *(bf16x8*)(dh + i * 8) = vh[i];
        *(bf16x8*)(dl + i * 8) = vl[i];
    }
    hp[t] = 0.5f * c2;
}

// ---- kernel 2: MFMA scores + per-(pos,m) top-2 over all 2048 codes ----
// block = 256 thr = 4 waves; wave = m; wave covers 64 positions (4 groups of 16).
// A = codebook tile (16 codes x 32 d), B = q^T (32 d x 16 pos).
// C/D layout: col = lane&15 = position, row = (lane>>4)*4 + reg = code-in-tile.
__global__ __launch_bounds__(256) void score_kernel(const float* __restrict__ latent,
        const unsigned char* __restrict__ ws,
        int* __restrict__ k1o, int* __restrict__ k2o) {
    __shared__ float s_h[M_ * K_];   // 32 KiB
    const int tid = threadIdx.x;
    {   // stage h into LDS
        const float4* src = (const float4*)(ws + H_OFF);
        float4* dst = (float4*)s_h;
        #pragma unroll
        for (int i = 0; i < 8; ++i) dst[tid + i * 256] = src[tid + i * 256];
    }
    __syncthreads();

    const int m    = tid >> 6;
    const int L    = tid & 63;
    const int col  = L & 15;       // A: code row in tile; B: position column
    const int krow = L >> 4;       // k-group (d-slice for inputs, code-row-group for C)
    const int posbase = blockIdx.x * 64;
    const int n   = posbase >> 12;         // 64 | 4096 -> block never straddles n
    const int hwb = posbase & (HW_ - 1);

    // load q (fp32, once) and split into bf16 hi/lo B-fragments
    bf16x8 qh[4], ql[4];
    const float* lp = latent + ((size_t)n * (M_ * D_) + m * D_) * HW_ + hwb;
    #pragma unroll
    for (int g = 0; g < 4; ++g) {
        #pragma unroll
        for (int j = 0; j < 8; ++j) {
            float x = lp[(size_t)(krow * 8 + j) * HW_ + g * 16 + col];
            float hf, lf;
            short hb = bf16_rte(x, &hf);
            short lb = bf16_rte(x - hf, &lf);
            qh[g][j] = hb;
            ql[g][j] = lb;
        }
    }

    const short* ah = (const short*)(ws + CBH_OFF) + ((size_t)m * K_ + col) * D_ + krow * 8;
    const short* al = (const short*)(ws + CBL_OFF) + ((size_t)m * K_ + col) * D_ + krow * 8;

    float b1[4], b2[4]; int k1[4], k2[4];
    #pragma unroll
    for (int g = 0; g < 4; ++g) { b1[g] = b2[g] = -3.402823466e+38f; k1[g] = k2[g] = 0; }

    int kb = krow * 4;   // code index base for reg r: k = kb + r; += 16 per tile

    #pragma unroll 2
    for (int t = 0; t < NT; ++t) {
        bf16x8 ch = *(const bf16x8*)(ah + (size_t)t * (16 * D_));
        bf16x8 cl = *(const bf16x8*)(al + (size_t)t * (16 * D_));
        f32x4 mh = *(const f32x4*)&s_h[m * K_ + t * 16 + krow * 4];
        f32x4 c0;
        c0[0] = -mh[0]; c0[1] = -mh[1]; c0[2] = -mh[2]; c0[3] = -mh[3];
        #pragma unroll
        for (int g = 0; g < 4; ++g) {
            // 3-term split: (ch+cl)*(qh+ql) minus cl*ql  ->  err ~1e-5, rescued by rescore
            f32x4 a = __builtin_amdgcn_mfma_f32_16x16x32_bf16(cl, qh[g], c0, 0, 0, 0);
            a = __builtin_amdgcn_mfma_f32_16x16x32_bf16(ch, ql[g], a, 0, 0, 0);
            a = __builtin_amdgcn_mfma_f32_16x16x32_bf16(ch, qh[g], a, 0, 0, 0);
            #pragma unroll
            for (int r = 0; r < 4; ++r) {
                float s = a[r];
                int kr = kb + r;
                bool gt = s > b1[g];                 // strict >: first-max wins
                float ss = gt ? b1[g] : s;
                int   sk = gt ? k1[g] : kr;
                b1[g] = gt ? s  : b1[g];
                k1[g] = gt ? kr : k1[g];
                bool g2 = ss > b2[g];
                b2[g] = g2 ? ss : b2[g];
                k2[g] = g2 ? sk : k2[g];
            }
        }
        kb += 16;
    }

    // merge top-2 across the 4 code-row lane-groups (butterfly xor 16, 32)
    #pragma unroll
    for (int g = 0; g < 4; ++g) {
        #pragma unroll
        for (int off = 16; off <= 32; off <<= 1) {
            float ob1 = __shfl_xor(b1[g], off);
            int   ok1 = __shfl_xor(k1[g], off);
            float ob2 = __shfl_xor(b2[g], off);
            int   ok2 = __shfl_xor(k2[g], off);
            bool awin = (b1[g] > ob1) || (b1[g] == ob1 && k1[g] < ok1);
            float ts = awin ? b1[g] : ob1;  int tk = awin ? k1[g] : ok1;
            float ls = awin ? ob1 : b1[g];  int lk = awin ? ok1 : k1[g];
            float ms = awin ? b2[g] : ob2;  int mk = awin ? k2[g] : ok2;
            bool lwin = (ls > ms) || (ls == ms && lk < mk);
            b1[g] = ts; k1[g] = tk;
            b2[g] = lwin ? ls : ms;
            k2[g] = lwin ? lk : mk;
        }
        if (L < 16) {
            int pos = posbase + g * 16 + L;
            k1o[m * NHW_ + pos] = k1[g];
            k2o[m * NHW_ + pos] = k2[g];
        }
    }
}

// ---- kernel 3: exact fp32 rescore of the two candidates, pick winner ----
__device__ __forceinline__ float score_fp32(const float* __restrict__ q,
                                            const float4* __restrict__ c) {
    float d0 = 0, d1 = 0, d2 = 0, d3 = 0, e0 = 0, e1 = 0, e2 = 0, e3 = 0;
    #pragma unroll
    for (int v = 0; v < 8; ++v) {
        float4 cv = c[v];
        d0 = fmaf(q[v * 4 + 0], cv.x, d0);
        d1 = fmaf(q[v * 4 + 1], cv.y, d1);
        d2 = fmaf(q[v * 4 + 2], cv.z, d2);
        d3 = fmaf(q[v * 4 + 3], cv.w, d3);
        e0 = fmaf(cv.x, cv.x, e0);
        e1 = fmaf(cv.y, cv.y, e1);
        e2 = fmaf(cv.z, cv.z, e2);
        e3 = fmaf(cv.w, cv.w, e3);
    }
    return ((d0 + d1) + (d2 + d3)) - 0.5f * ((e0 + e1) + (e2 + e3));
}

__global__ __launch_bounds__(256) void rescore_kernel(const float* __restrict__ latent,
        const float* __restrict__ cb, const unsigned char* __restrict__ ws,
        int* __restrict__ out) {
    int t = blockIdx.x * 256 + threadIdx.x;     // 0..131071 = m*NHW_ + pos
    int m = t >> 15;
    int pos = t & (NHW_ - 1);
    int n = pos >> 12;
    int hw = pos & (HW_ - 1);
    const int* k1a = (const int*)(ws + K1_OFF);
    const int* k2a = (const int*)(ws + K2_OFF);
    int k1 = k1a[t], k2 = k2a[t];
    const float* lp = latent + ((size_t)n * (M_ * D_) + m * D_) * HW_ + hw;
    float q[D_];
    #pragma unroll
    for (int d = 0; d < D_; ++d) q[d] = lp[(size_t)d * HW_];
    float s1 = score_fp32(q, (const float4*)(cb + ((size_t)m * K_ + k1) * D_));
    float s2 = score_fp32(q, (const float4*)(cb + ((size_t)m * K_ + k2) * D_));
    int win = (s2 > s1 || (s2 == s1 && k2 < k1)) ? k2 : k1;
    out[(size_t)pos * M_ + m] = win;
}

extern "C" void kernel_launch(void* const* d_in, const int* in_sizes, int n_in,
                              void* d_out, int out_size, void* d_ws, size_t ws_size,
                              hipStream_t stream) {
    const float* latent   = (const float*)d_in[0];
    const float* codebook = (const float*)d_in[1];
    unsigned char* ws = (unsigned char*)d_ws;
    int* out = (int*)d_out;
    prep_kernel<<<(M_ * K_) / 256, 256, 0, stream>>>(codebook, ws);
    score_kernel<<<NHW_ / 64, 256, 0, stream>>>(latent, ws,
                                                (int*)(ws + K1_OFF), (int*)(ws + K2_OFF));
    rescore_kernel<<<(NHW_ * M_) / 256, 256, 0, stream>>>(latent, codebook, ws, out);
}